// Round 7
// baseline (211.154 us; speedup 1.0000x reference)
//
#include <hip/hip_runtime.h>
#include <stdint.h>

#pragma clang fp contract(off)

#define NUM_CLASSES 81
#define TOP_K 200
#define BATCH 32
#define NUM_PRIORS 16384
#define CAP 512
#define CONF_T 0.01f
#define NMS_T 0.45f
#define PIVOT_S 0.97827148f
#define NTASK (BATCH * (NUM_CLASSES - 1))
#define QCAP 768                // mean ~222 hits/block, +36 sigma headroom
#define ROWS_PER_BLK 128
#define FILTER_BLOCKS 4096      // 128 chunks x 32 images

typedef unsigned long long u64;
typedef unsigned int u32;

// Correctly-rounded f32 exp via f64 — verified bit-compatible R0-R5 (absmax 3e-8).
__device__ __forceinline__ float exp_ref(float x) {
#pragma clang fp contract(off)
    return (float)exp((double)x);
}

struct SharedBlk {
    u64 keys[CAP];          // canonical keys: bits(score)<<32 | (u32)(~p)
    u64 sup[TOP_K][4];      // suppression bitmask rows (bits k>j with iou>thr)
    float box[TOP_K][5];    // x1,y1,x2,y2,area — 20B stride: gcd(5,32)=1 -> conflict-free
    float score[TOP_K];
    u64 keep[4];
    u32 acc;                // count accumulator
    u32 ctr;                // gather append counter
};

// Count elements with key > pivot (valid = score > CONF_T; invalid key == 0).
__device__ int count_pass(const float* cbase, u64 pivot, int tid, int lane, u32* s_acc) {
#pragma clang fp contract(off)
    __syncthreads();
    if (tid == 0) *s_acc = 0u;
    __syncthreads();
    u32 ph = (u32)(pivot >> 32), pl = (u32)pivot;
    u32 c = 0;
    for (int j = 0; j < 64; ++j) {
        int p = tid + (j << 8);
        float s = cbase[(size_t)p * NUM_CLASSES];
        bool valid = s > CONF_T;
        u32 bt = valid ? __float_as_uint(s) : 0u;
        u32 il = ~(u32)p;
        c += (valid && ((bt > ph) || ((bt == ph) && (il > pl)))) ? 1u : 0u;
    }
    for (int off = 32; off > 0; off >>= 1) c += __shfl_down(c, off, 64);
    if (lane == 0) atomicAdd(s_acc, c);
    __syncthreads();
    return (int)*s_acc;
}

// Count AND gather (capped at CAP) elements with key > pivot into s_keys.
__device__ int gather_pass(const float* cbase, u64 pivot, int tid, int lane,
                           u64* s_keys, u32* s_acc, u32* s_ctr) {
#pragma clang fp contract(off)
    __syncthreads();
    if (tid == 0) { *s_acc = 0u; *s_ctr = 0u; }
    for (int q = tid; q < CAP; q += 256) s_keys[q] = 0ull;
    __syncthreads();
    u32 ph = (u32)(pivot >> 32), pl = (u32)pivot;
    u32 cnt = 0;
    for (int j = 0; j < 64; ++j) {
        int p = tid + (j << 8);
        float s = cbase[(size_t)p * NUM_CLASSES];
        bool valid = s > CONF_T;
        u32 bt = valid ? __float_as_uint(s) : 0u;
        u32 il = ~(u32)p;
        bool pred = valid && ((bt > ph) || ((bt == ph) && (il > pl)));
        cnt += pred ? 1u : 0u;
        u64 mk = __ballot(pred);
        u32 off = 0;
        if (lane == 0 && mk) off = atomicAdd(s_ctr, (u32)__popcll(mk));
        off = __shfl(off, 0, 64);
        if (pred) {
            u32 pos = off + (u32)__popcll(mk & ((1ull << lane) - 1ull));
            if (pos < CAP) s_keys[pos] = ((u64)bt << 32) | il;
        }
    }
    for (int off2 = 32; off2 > 0; off2 >>= 1) cnt += __shfl_down(cnt, off2, 64);
    if (lane == 0) atomicAdd(s_acc, cnt);
    __syncthreads();
    return (int)*s_acc;
}

// ---- Kernel 1: coalesced filter, two-pass over live registers.
// Streaming path has ZERO cross-lane ops: pass 1 counts hits branch-free,
// one LDS atomic per THREAD reserves a queue span, pass 2 re-derives hits
// from the still-live registers (forces all 10 loads to stay hoisted -> MLP)
// and writes keys with plain exec-masked LDS stores. Flush: XCD-local global
// atomics (img = bid&31 -> bid%8 = fixed XCD).
__global__ __launch_bounds__(256) void filter_kernel(
    const float4* __restrict__ conf4,
    u32* __restrict__ counts, u64* __restrict__ keys)
{
#pragma clang fp contract(off)
    __shared__ u64 qkey[QCAP];
    __shared__ u32 qn;

    const int tid = threadIdx.x;
    const int bid = blockIdx.x;
    const int img = bid & 31;        // image pinned to one XCD (bid%8 fixed)
    const int chunk = bid >> 5;      // 128 chunks x 128 prior-rows
    const int row0 = img * NUM_PRIORS + chunk * ROWS_PER_BLK;
    const int base4 = row0 * NUM_CLASSES / 4;   // 128*81 = 10368 elems = 2592 float4

    if (tid == 0) qn = 0u;
    __syncthreads();

    // 2592 float4 = 10*256 + 32: all loads up front, kept live for both passes.
    float4 v[10];
    #pragma unroll
    for (int g = 0; g < 10; ++g)
        v[g] = conf4[base4 + tid + g * 256];
    float4 vt = make_float4(0.f, 0.f, 0.f, 0.f);
    if (tid < 32) vt = conf4[base4 + tid + 2560];

    // ---- Pass 1: branch-free per-thread hit count (no LDS, no cross-lane).
    u32 cnt = 0;
    #pragma unroll
    for (int g = 0; g < 11; ++g) {
        float vv[4];
        if (g < 10) { vv[0]=v[g].x; vv[1]=v[g].y; vv[2]=v[g].z; vv[3]=v[g].w; }
        else        { vv[0]=vt.x;  vv[1]=vt.y;  vv[2]=vt.z;  vv[3]=vt.w; }
        int le4 = tid + g * 256;
        #pragma unroll
        for (int j = 0; j < 4; ++j) {
            u32 le = (u32)(le4 * 4 + j);
            u32 lrow = le / NUM_CLASSES;            // magic-mul
            u32 c = le - lrow * NUM_CLASSES;
            cnt += (vv[j] > PIVOT_S && c != 0u) ? 1u : 0u;
        }
    }

    // One LDS atomic per thread (outside the stream) reserves the span.
    u32 wpos = atomicAdd(&qn, cnt);

    // ---- Pass 2: re-derive hits from live registers, write reserved slots.
    #pragma unroll
    for (int g = 0; g < 11; ++g) {
        float vv[4];
        if (g < 10) { vv[0]=v[g].x; vv[1]=v[g].y; vv[2]=v[g].z; vv[3]=v[g].w; }
        else        { vv[0]=vt.x;  vv[1]=vt.y;  vv[2]=vt.z;  vv[3]=vt.w; }
        int le4 = tid + g * 256;
        #pragma unroll
        for (int j = 0; j < 4; ++j) {
            float s = vv[j];
            if (s > PIVOT_S) {                       // rare (~2.2%/elem)
                u32 le = (u32)(le4 * 4 + j);
                u32 lrow = le / NUM_CLASSES;
                u32 c = le - lrow * NUM_CLASSES;
                if (c != 0u) {
                    u32 p = (u32)(chunk * ROWS_PER_BLK) + lrow;   // prior idx in image
                    u64 key = ((u64)__float_as_uint(s) << 32)
                            | ((u64)(16383u - p) << 7) | (u64)(c - 1u);
                    if (wpos < QCAP) qkey[wpos] = key;
                    ++wpos;
                }
            }
        }
    }
    __syncthreads();

    u32 qtotal = qn;
    u32 qvalid = qtotal < QCAP ? qtotal : QCAP;
    // flush: global atomics, all to this image's counters (XCD-local L2)
    for (u32 q = tid; q < qvalid; q += 256) {
        u64 k = qkey[q];
        u32 t = (u32)img * 80u + (u32)(k & 0x7Full);
        u32 slot = atomicAdd(&counts[t], 1u);
        if (slot < CAP) keys[(size_t)t * CAP + slot] = k;
    }
    if (qtotal > QCAP) {
        // ~36-sigma event: poison this image's counts -> nms exact fallback
        if (tid < 80) atomicAdd(&counts[img * 80 + tid], 0x01000000u);
    }
}

// ---- Kernel 2: per-(img,class) sort + NMS. Fast path reads keys from ws;
// exact fallback (count outside [TOP_K, CAP]) re-scans the conf column.
__global__ __launch_bounds__(256) void nms_kernel(
    const float* __restrict__ loc_data,   // [B,P,4]
    const float* __restrict__ conf_data,  // [B*P,C]
    const float* __restrict__ prior_data, // [P,4]
    const u32* __restrict__ counts,       // [NTASK] (may be null)
    const u64* __restrict__ gkeys,        // [NTASK][CAP] (may be null)
    float* __restrict__ out,              // [B,C,K,5], pre-zeroed
    int use_ws)
{
#pragma clang fp contract(off)
    __shared__ SharedBlk sh;
    const int tid = threadIdx.x;
    const int lane = tid & 63;
    const int wv = tid >> 6;
    const int b = blockIdx.x;
    const int img = b / 80;
    const int r = b - img * 80;
    const int cl = r + 1;
    const int task = img * 80 + r;

    const float* cbase = conf_data + (size_t)img * NUM_PRIORS * NUM_CLASSES + cl;

    // ---- Phase 1: candidate set (ws fast path, else exact strided fallback)
    int m = -1;
    if (use_ws) {
        u32 cnt = counts[task];
        if (cnt >= TOP_K && cnt <= CAP) {
            const u64* src = gkeys + (size_t)task * CAP;
            for (int q = tid; q < CAP; q += 256) {
                u64 k = 0ull;
                if (q < (int)cnt) {
                    u64 kw = src[q];
                    u32 p = 16383u - ((u32)(kw >> 7) & 0x3FFFu);
                    k = (kw & 0xFFFFFFFF00000000ull) | (u64)(u32)(~p);
                }
                sh.keys[q] = k;
            }
            m = (int)cnt;
        }
    }
    if (m < 0) {
        u64 pivot = ((u64)__float_as_uint(PIVOT_S) << 32) | 0xFFFFFFFFull;
        m = gather_pass(cbase, pivot, tid, lane, sh.keys, &sh.acc, &sh.ctr);
        if (m < TOP_K || m > CAP) {
            const u32 B001 = __float_as_uint(CONF_T);
            int nvalid = count_pass(cbase, ((u64)B001 << 32) | 0xFFFFFFFFull, tid, lane, &sh.acc);
            if (nvalid <= CAP) {
                pivot = 0ull;  // gather all valid
            } else {
                u64 lo = ((u64)B001 << 32) | 0xFFFFFFFFull;
                u64 hi = ~0ull;
                for (int it = 0; it < 64; ++it) {
                    u64 mid = lo + ((hi - lo) >> 1);
                    int c = count_pass(cbase, mid, tid, lane, &sh.acc);
                    if (c >= TOP_K && c <= CAP) { pivot = mid; break; }
                    if (c > CAP) lo = mid; else hi = mid;
                }
            }
            m = gather_pass(cbase, pivot, tid, lane, sh.keys, &sh.acc, &sh.ctr);
        }
    }
    const int nk = m < TOP_K ? m : TOP_K;

    // ---- Phase 2: bitonic sort CAP keys descending (keys distinct)
    for (int k2 = 2; k2 <= CAP; k2 <<= 1) {
        for (int jj = k2 >> 1; jj > 0; jj >>= 1) {
            __syncthreads();
            for (int i = tid; i < CAP; i += 256) {
                int ixj = i ^ jj;
                if (ixj > i) {
                    u64 a = sh.keys[i], bb = sh.keys[ixj];
                    bool up = ((i & k2) == 0);
                    if (up ? (a < bb) : (a > bb)) { sh.keys[i] = bb; sh.keys[ixj] = a; }
                }
            }
        }
    }
    __syncthreads();

    // ---- Phase 3: decode candidate boxes (reference op order)
    if (tid < nk) {
        u64 key = sh.keys[tid];
        int p = (int)(~(u32)key);
        float sc = __uint_as_float((u32)(key >> 32));
        const float4 lc = *(const float4*)(loc_data + ((size_t)img * NUM_PRIORS + p) * 4);
        const float4 pr = *(const float4*)(prior_data + (size_t)p * 4);
        float cx = pr.x + (lc.x * 0.1f) * pr.z;
        float cy = pr.y + (lc.y * 0.1f) * pr.w;
        float w  = pr.z * exp_ref(lc.z * 0.2f);
        float h  = pr.w * exp_ref(lc.w * 0.2f);
        float x1 = cx - 0.5f * w;
        float y1 = cy - 0.5f * h;
        float x2 = x1 + w;
        float y2 = y1 + h;
        sh.box[tid][0] = x1; sh.box[tid][1] = y1; sh.box[tid][2] = x2; sh.box[tid][3] = y2;
        sh.box[tid][4] = fmaxf(x2 - x1, 0.0f) * fmaxf(y2 - y1, 0.0f);
        sh.score[tid] = sc;
    }
    __syncthreads();

    // ---- Phase 4: row-per-thread suppression masks (upper triangle, regs only)
    {
        u64 m0 = 0ull, m1 = 0ull, m2 = 0ull, m3 = 0ull;
        if (tid < nk) {
            const float bx0 = sh.box[tid][0], by0 = sh.box[tid][1];
            const float bx1 = sh.box[tid][2], by1 = sh.box[tid][3];
            const float aj  = sh.box[tid][4];
            #pragma unroll
            for (int c = 0; c < 4; ++c) {
                u64 mm = 0ull;
                int klo = tid + 1 > (c << 6) ? tid + 1 : (c << 6);
                int khi = nk < ((c + 1) << 6) ? nk : ((c + 1) << 6);
                for (int k = klo; k < khi; ++k) {
                    float ltx = fmaxf(bx0, sh.box[k][0]);
                    float lty = fmaxf(by0, sh.box[k][1]);
                    float rbx = fminf(bx1, sh.box[k][2]);
                    float rby = fminf(by1, sh.box[k][3]);
                    float wx = fmaxf(rbx - ltx, 0.0f);
                    float wy = fmaxf(rby - lty, 0.0f);
                    float inter = wx * wy;
                    float uni = (aj + sh.box[k][4]) - inter;
                    float iou = inter / fmaxf(uni, 1e-12f);
                    if (iou > NMS_T) mm |= 1ull << (k & 63);
                }
                if (c == 0) m0 = mm; else if (c == 1) m1 = mm;
                else if (c == 2) m2 = mm; else m3 = mm;
            }
        }
        if (tid < TOP_K) {
            sh.sup[tid][0] = m0; sh.sup[tid][1] = m1;
            sh.sup[tid][2] = m2; sh.sup[tid][3] = m3;
        }
    }
    __syncthreads();

    // ---- Phase 5: greedy resolve on wave 0 (64-bit chunks, shfl broadcast)
    if (wv == 0) {
        u64 kws[4];
        #pragma unroll
        for (int w = 0; w < 4; ++w) {
            int rem = nk - (w << 6);
            kws[w] = rem >= 64 ? ~0ull : (rem <= 0 ? 0ull : ((1ull << rem) - 1ull));
        }
        for (int c = 0; c < 4; ++c) {
            int row = (c << 6) + lane;
            u64 myrow = (row < TOP_K) ? sh.sup[row][c] : 0ull;
            u64 kw = kws[c];
            u64 nz = __ballot(myrow != 0ull);
            u64 t = kw & nz;
            while (t) {
                int j = __ffsll(t) - 1;
                u64 rj = __shfl(myrow, j, 64);
                kw &= ~rj;
                t &= ~(1ull << j);
                t &= kw;
            }
            kws[c] = kw;
            for (int w2 = c + 1; w2 < 4; ++w2) {
                u64 contrib = (row < TOP_K && ((kw >> lane) & 1ull)) ? sh.sup[row][w2] : 0ull;
                #pragma unroll
                for (int off = 32; off > 0; off >>= 1) contrib |= __shfl_xor(contrib, off, 64);
                kws[w2] &= ~contrib;
            }
        }
        if (lane == 0) {
            sh.keep[0] = kws[0]; sh.keep[1] = kws[1];
            sh.keep[2] = kws[2]; sh.keep[3] = kws[3];
        }
    }
    __syncthreads();

    // ---- Phase 6: stable compaction of kept rows
    if (tid < nk) {
        int w = tid >> 6, rr = tid & 63;
        u64 kwv = sh.keep[w];
        if ((kwv >> rr) & 1ull) {
            int pos = __popcll(kwv & ((1ull << rr) - 1ull));
            for (int q = 0; q < w; ++q) pos += __popcll(sh.keep[q]);
            float* o = out + (((size_t)img * NUM_CLASSES + cl) * TOP_K + pos) * 5;
            o[0] = sh.score[tid];
            o[1] = sh.box[tid][0];
            o[2] = sh.box[tid][1];
            o[3] = sh.box[tid][2];
            o[4] = sh.box[tid][3];
        }
    }
}

extern "C" void kernel_launch(void* const* d_in, const int* in_sizes, int n_in,
                              void* d_out, int out_size, void* d_ws, size_t ws_size,
                              hipStream_t stream) {
    const float* loc   = (const float*)d_in[0];
    const float* conf  = (const float*)d_in[1];
    const float* prior = (const float*)d_in[2];
    float* out = (float*)d_out;

    hipMemsetAsync(d_out, 0, (size_t)out_size * sizeof(float), stream);

    // ws layout: [0, NTASK*4) counts | [65536, 65536 + NTASK*CAP*8) keys
    const size_t need = 65536 + (size_t)NTASK * CAP * 8;
    const int use_ws = (ws_size >= need) ? 1 : 0;   // constant per session -> deterministic

    u32* counts = (u32*)d_ws;
    u64* keys   = (u64*)((char*)d_ws + 65536);

    if (use_ws) {
        hipMemsetAsync(d_ws, 0, NTASK * sizeof(u32), stream);
        filter_kernel<<<FILTER_BLOCKS, 256, 0, stream>>>((const float4*)conf, counts, keys);
    }
    nms_kernel<<<NTASK, 256, 0, stream>>>(loc, conf, prior,
                                          use_ws ? counts : nullptr,
                                          use_ws ? keys : nullptr,
                                          out, use_ws);
}

// Round 8
// 149.226 us; speedup vs baseline: 1.4150x; 1.4150x over previous
//
#include <hip/hip_runtime.h>
#include <stdint.h>

#pragma clang fp contract(off)

#define NUM_CLASSES 81
#define TOP_K 200
#define BATCH 32
#define NUM_PRIORS 16384
#define CAP 512
#define CONF_T 0.01f
#define NMS_T 0.45f
#define PIVOT_S 0.97827148f
#define NTASK (BATCH * (NUM_CLASSES - 1))
#define QCAP 1536               // mean ~445 hits/block (256 rows), +50 sigma headroom
#define ROWS_PER_BLK 256
#define FILTER_BLOCKS 2048      // 64 chunks x 32 images

typedef unsigned long long u64;
typedef unsigned int u32;

// Correctly-rounded f32 exp via f64 — verified bit-compatible R0-R6 (absmax 3e-8).
__device__ __forceinline__ float exp_ref(float x) {
#pragma clang fp contract(off)
    return (float)exp((double)x);
}

struct SharedBlk {
    u64 keys[CAP];          // canonical keys: bits(score)<<32 | (u32)(~p)
    u64 sup[TOP_K][4];      // suppression bitmask rows (bits k>j with iou>thr)
    float box[TOP_K][5];    // x1,y1,x2,y2,area — 20B stride: gcd(5,32)=1 -> conflict-free
    float score[TOP_K];
    u64 keep[4];
    u32 acc;                // count accumulator
    u32 ctr;                // gather append counter
};

// Count elements with key > pivot (valid = score > CONF_T; invalid key == 0).
__device__ int count_pass(const float* cbase, u64 pivot, int tid, int lane, u32* s_acc) {
#pragma clang fp contract(off)
    __syncthreads();
    if (tid == 0) *s_acc = 0u;
    __syncthreads();
    u32 ph = (u32)(pivot >> 32), pl = (u32)pivot;
    u32 c = 0;
    for (int j = 0; j < 64; ++j) {
        int p = tid + (j << 8);
        float s = cbase[(size_t)p * NUM_CLASSES];
        bool valid = s > CONF_T;
        u32 bt = valid ? __float_as_uint(s) : 0u;
        u32 il = ~(u32)p;
        c += (valid && ((bt > ph) || ((bt == ph) && (il > pl)))) ? 1u : 0u;
    }
    for (int off = 32; off > 0; off >>= 1) c += __shfl_down(c, off, 64);
    if (lane == 0) atomicAdd(s_acc, c);
    __syncthreads();
    return (int)*s_acc;
}

// Count AND gather (capped at CAP) elements with key > pivot into s_keys.
__device__ int gather_pass(const float* cbase, u64 pivot, int tid, int lane,
                           u64* s_keys, u32* s_acc, u32* s_ctr) {
#pragma clang fp contract(off)
    __syncthreads();
    if (tid == 0) { *s_acc = 0u; *s_ctr = 0u; }
    for (int q = tid; q < CAP; q += 256) s_keys[q] = 0ull;
    __syncthreads();
    u32 ph = (u32)(pivot >> 32), pl = (u32)pivot;
    u32 cnt = 0;
    for (int j = 0; j < 64; ++j) {
        int p = tid + (j << 8);
        float s = cbase[(size_t)p * NUM_CLASSES];
        bool valid = s > CONF_T;
        u32 bt = valid ? __float_as_uint(s) : 0u;
        u32 il = ~(u32)p;
        bool pred = valid && ((bt > ph) || ((bt == ph) && (il > pl)));
        cnt += pred ? 1u : 0u;
        u64 mk = __ballot(pred);
        u32 off = 0;
        if (lane == 0 && mk) off = atomicAdd(s_ctr, (u32)__popcll(mk));
        off = __shfl(off, 0, 64);
        if (pred) {
            u32 pos = off + (u32)__popcll(mk & ((1ull << lane) - 1ull));
            if (pos < CAP) s_keys[pos] = ((u64)bt << 32) | il;
        }
    }
    for (int off2 = 32; off2 > 0; off2 >>= 1) cnt += __shfl_down(cnt, off2, 64);
    if (lane == 0) atomicAdd(s_acc, cnt);
    __syncthreads();
    return (int)*s_acc;
}

// ---- Kernel 1: coalesced filter (R2 structure: in-loop loads so the compiler
// software-pipelines with fine vmcnt; ONE ballot-chain per float4 group).
// Flush: per-task span reservation — 80 global atomics/block instead of ~450.
__global__ __launch_bounds__(256) void filter_kernel(
    const float4* __restrict__ conf4,
    u32* __restrict__ counts, u64* __restrict__ keys)
{
#pragma clang fp contract(off)
    __shared__ u64 qkey[QCAP];
    __shared__ u32 tcnt[80];
    __shared__ u32 qn;

    const int tid = threadIdx.x;
    const int lane = tid & 63;
    const int bid = blockIdx.x;
    const int img = bid & 31;        // image pinned to one XCD (bid%8 fixed)
    const int chunk = bid >> 5;      // 64 chunks x 256 prior-rows
    const int row0 = img * NUM_PRIORS + chunk * ROWS_PER_BLK;
    const int base4 = row0 * NUM_CLASSES / 4;   // 256*81 = 20736 elems = 5184 float4

    if (tid == 0) qn = 0u;
    if (tid < 80) tcnt[tid] = 0u;
    __syncthreads();

    // 5184 float4 = 20*256 + 64
    #pragma unroll 4
    for (int it = 0; it < 21; ++it) {
        int le4 = tid + it * 256;
        if (it == 20 && tid >= 64) break;
        float4 v = conf4[base4 + le4];
        float vv[4] = {v.x, v.y, v.z, v.w};

        // per-lane hit flags + count (branch-free; no cross-lane yet)
        bool h0, h1, h2, h3;
        {
            u32 le0 = (u32)(le4 * 4);
            u32 r0 = le0 / NUM_CLASSES;            // magic-mul
            u32 c0 = le0 - r0 * NUM_CLASSES;
            h0 = (vv[0] > PIVOT_S) && (c0 != 0u);
            u32 c1 = c0 + 1u, c2 = c0 + 2u, c3 = c0 + 3u;
            h1 = (vv[1] > PIVOT_S) && (c1 != 81u);  // c1 in [1,81]; 81 means class 0
            h2 = (vv[2] > PIVOT_S) && (c2 != 81u) && (c2 != 162u);
            h3 = (vv[3] > PIVOT_S) && (c3 != 81u) && (c3 != 162u);
        }
        u32 hc = (h0?1u:0u) + (h1?1u:0u) + (h2?1u:0u) + (h3?1u:0u);

        // ONE aggregation per group: 4 independent ballots -> 1 atomic -> 1 shfl
        u64 b1 = __ballot(hc >= 1u);
        if (b1) {
            u64 b2 = __ballot(hc >= 2u);
            u64 b3 = __ballot(hc >= 3u);
            u64 b4 = __ballot(hc >= 4u);
            u32 tot = (u32)(__popcll(b1) + __popcll(b2) + __popcll(b3) + __popcll(b4));
            u32 base = 0;
            if (lane == 0) base = atomicAdd(&qn, tot);
            base = __shfl(base, 0, 64);
            if (hc) {
                u64 lt = (1ull << lane) - 1ull;
                u32 off = base + (u32)(__popcll(b1 & lt) + __popcll(b2 & lt)
                                     + __popcll(b3 & lt) + __popcll(b4 & lt));
                #pragma unroll
                for (int j = 0; j < 4; ++j) {
                    bool hj = (j == 0) ? h0 : (j == 1) ? h1 : (j == 2) ? h2 : h3;
                    if (hj) {
                        u32 le = (u32)(le4 * 4 + j);
                        u32 lrow = le / NUM_CLASSES;
                        u32 c = le - lrow * NUM_CLASSES;
                        u32 p = (u32)(chunk * ROWS_PER_BLK) + lrow;  // prior idx in image
                        u64 key = ((u64)__float_as_uint(vv[j]) << 32)
                                | ((u64)(16383u - p) << 7) | (u64)(c - 1u);
                        if (off < QCAP) qkey[off] = key;
                        ++off;
                    }
                }
            }
        }
    }
    __syncthreads();

    u32 qtotal = qn;
    u32 qvalid = qtotal < QCAP ? qtotal : QCAP;

    // ---- Flush stage A: per-task histogram in LDS
    for (u32 q = tid; q < qvalid; q += 256)
        atomicAdd(&tcnt[(u32)(qkey[q] & 0x7Full)], 1u);
    __syncthreads();

    // ---- Flush stage B: ONE global atomic per non-empty task (XCD-local L2)
    if (tid < 80) {
        u32 n = tcnt[tid];
        u32 base = 0;
        if (n) base = atomicAdd(&counts[img * 80 + tid], n);
        tcnt[tid] = base;                    // reuse as scatter cursor
    }
    __syncthreads();

    // ---- Flush stage C: scatter keys at reserved spans (LDS cursors)
    for (u32 q = tid; q < qvalid; q += 256) {
        u64 k = qkey[q];
        u32 t = (u32)(k & 0x7Full);
        u32 slot = atomicAdd(&tcnt[t], 1u);  // LDS atomic
        if (slot < CAP) keys[(size_t)(img * 80 + t) * CAP + slot] = k;
    }
    if (qtotal > QCAP) {
        // ~50-sigma event: poison this image's counts -> nms exact fallback
        if (tid < 80) atomicAdd(&counts[img * 80 + tid], 0x01000000u);
    }
}

// ---- Kernel 2: per-(img,class) sort + NMS. Fast path reads keys from ws;
// exact fallback (count outside [TOP_K, CAP]) re-scans the conf column.
__global__ __launch_bounds__(256) void nms_kernel(
    const float* __restrict__ loc_data,   // [B,P,4]
    const float* __restrict__ conf_data,  // [B*P,C]
    const float* __restrict__ prior_data, // [P,4]
    const u32* __restrict__ counts,       // [NTASK] (may be null)
    const u64* __restrict__ gkeys,        // [NTASK][CAP] (may be null)
    float* __restrict__ out,              // [B,C,K,5], pre-zeroed
    int use_ws)
{
#pragma clang fp contract(off)
    __shared__ SharedBlk sh;
    const int tid = threadIdx.x;
    const int lane = tid & 63;
    const int wv = tid >> 6;
    const int b = blockIdx.x;
    const int img = b / 80;
    const int r = b - img * 80;
    const int cl = r + 1;
    const int task = img * 80 + r;

    const float* cbase = conf_data + (size_t)img * NUM_PRIORS * NUM_CLASSES + cl;

    // ---- Phase 1: candidate set (ws fast path, else exact strided fallback)
    int m = -1;
    if (use_ws) {
        u32 cnt = counts[task];
        if (cnt >= TOP_K && cnt <= CAP) {
            const u64* src = gkeys + (size_t)task * CAP;
            for (int q = tid; q < CAP; q += 256) {
                u64 k = 0ull;
                if (q < (int)cnt) {
                    u64 kw = src[q];
                    u32 p = 16383u - ((u32)(kw >> 7) & 0x3FFFu);
                    k = (kw & 0xFFFFFFFF00000000ull) | (u64)(u32)(~p);
                }
                sh.keys[q] = k;
            }
            m = (int)cnt;
        }
    }
    if (m < 0) {
        u64 pivot = ((u64)__float_as_uint(PIVOT_S) << 32) | 0xFFFFFFFFull;
        m = gather_pass(cbase, pivot, tid, lane, sh.keys, &sh.acc, &sh.ctr);
        if (m < TOP_K || m > CAP) {
            const u32 B001 = __float_as_uint(CONF_T);
            int nvalid = count_pass(cbase, ((u64)B001 << 32) | 0xFFFFFFFFull, tid, lane, &sh.acc);
            if (nvalid <= CAP) {
                pivot = 0ull;  // gather all valid
            } else {
                u64 lo = ((u64)B001 << 32) | 0xFFFFFFFFull;
                u64 hi = ~0ull;
                for (int it = 0; it < 64; ++it) {
                    u64 mid = lo + ((hi - lo) >> 1);
                    int c = count_pass(cbase, mid, tid, lane, &sh.acc);
                    if (c >= TOP_K && c <= CAP) { pivot = mid; break; }
                    if (c > CAP) lo = mid; else hi = mid;
                }
            }
            m = gather_pass(cbase, pivot, tid, lane, sh.keys, &sh.acc, &sh.ctr);
        }
    }
    const int nk = m < TOP_K ? m : TOP_K;

    // ---- Phase 2: bitonic sort CAP keys descending (keys distinct)
    for (int k2 = 2; k2 <= CAP; k2 <<= 1) {
        for (int jj = k2 >> 1; jj > 0; jj >>= 1) {
            __syncthreads();
            for (int i = tid; i < CAP; i += 256) {
                int ixj = i ^ jj;
                if (ixj > i) {
                    u64 a = sh.keys[i], bb = sh.keys[ixj];
                    bool up = ((i & k2) == 0);
                    if (up ? (a < bb) : (a > bb)) { sh.keys[i] = bb; sh.keys[ixj] = a; }
                }
            }
        }
    }
    __syncthreads();

    // ---- Phase 3: decode candidate boxes (reference op order)
    if (tid < nk) {
        u64 key = sh.keys[tid];
        int p = (int)(~(u32)key);
        float sc = __uint_as_float((u32)(key >> 32));
        const float4 lc = *(const float4*)(loc_data + ((size_t)img * NUM_PRIORS + p) * 4);
        const float4 pr = *(const float4*)(prior_data + (size_t)p * 4);
        float cx = pr.x + (lc.x * 0.1f) * pr.z;
        float cy = pr.y + (lc.y * 0.1f) * pr.w;
        float w  = pr.z * exp_ref(lc.z * 0.2f);
        float h  = pr.w * exp_ref(lc.w * 0.2f);
        float x1 = cx - 0.5f * w;
        float y1 = cy - 0.5f * h;
        float x2 = x1 + w;
        float y2 = y1 + h;
        sh.box[tid][0] = x1; sh.box[tid][1] = y1; sh.box[tid][2] = x2; sh.box[tid][3] = y2;
        sh.box[tid][4] = fmaxf(x2 - x1, 0.0f) * fmaxf(y2 - y1, 0.0f);
        sh.score[tid] = sc;
    }
    __syncthreads();

    // ---- Phase 4: row-per-thread suppression masks (upper triangle, regs only)
    {
        u64 m0 = 0ull, m1 = 0ull, m2 = 0ull, m3 = 0ull;
        if (tid < nk) {
            const float bx0 = sh.box[tid][0], by0 = sh.box[tid][1];
            const float bx1 = sh.box[tid][2], by1 = sh.box[tid][3];
            const float aj  = sh.box[tid][4];
            #pragma unroll
            for (int c = 0; c < 4; ++c) {
                u64 mm = 0ull;
                int klo = tid + 1 > (c << 6) ? tid + 1 : (c << 6);
                int khi = nk < ((c + 1) << 6) ? nk : ((c + 1) << 6);
                for (int k = klo; k < khi; ++k) {
                    float ltx = fmaxf(bx0, sh.box[k][0]);
                    float lty = fmaxf(by0, sh.box[k][1]);
                    float rbx = fminf(bx1, sh.box[k][2]);
                    float rby = fminf(by1, sh.box[k][3]);
                    float wx = fmaxf(rbx - ltx, 0.0f);
                    float wy = fmaxf(rby - lty, 0.0f);
                    float inter = wx * wy;
                    float uni = (aj + sh.box[k][4]) - inter;
                    float iou = inter / fmaxf(uni, 1e-12f);
                    if (iou > NMS_T) mm |= 1ull << (k & 63);
                }
                if (c == 0) m0 = mm; else if (c == 1) m1 = mm;
                else if (c == 2) m2 = mm; else m3 = mm;
            }
        }
        if (tid < TOP_K) {
            sh.sup[tid][0] = m0; sh.sup[tid][1] = m1;
            sh.sup[tid][2] = m2; sh.sup[tid][3] = m3;
        }
    }
    __syncthreads();

    // ---- Phase 5: greedy resolve on wave 0 (64-bit chunks, shfl broadcast)
    if (wv == 0) {
        u64 kws[4];
        #pragma unroll
        for (int w = 0; w < 4; ++w) {
            int rem = nk - (w << 6);
            kws[w] = rem >= 64 ? ~0ull : (rem <= 0 ? 0ull : ((1ull << rem) - 1ull));
        }
        for (int c = 0; c < 4; ++c) {
            int row = (c << 6) + lane;
            u64 myrow = (row < TOP_K) ? sh.sup[row][c] : 0ull;
            u64 kw = kws[c];
            u64 nz = __ballot(myrow != 0ull);
            u64 t = kw & nz;
            while (t) {
                int j = __ffsll(t) - 1;
                u64 rj = __shfl(myrow, j, 64);
                kw &= ~rj;
                t &= ~(1ull << j);
                t &= kw;
            }
            kws[c] = kw;
            for (int w2 = c + 1; w2 < 4; ++w2) {
                u64 contrib = (row < TOP_K && ((kw >> lane) & 1ull)) ? sh.sup[row][w2] : 0ull;
                #pragma unroll
                for (int off = 32; off > 0; off >>= 1) contrib |= __shfl_xor(contrib, off, 64);
                kws[w2] &= ~contrib;
            }
        }
        if (lane == 0) {
            sh.keep[0] = kws[0]; sh.keep[1] = kws[1];
            sh.keep[2] = kws[2]; sh.keep[3] = kws[3];
        }
    }
    __syncthreads();

    // ---- Phase 6: stable compaction of kept rows
    if (tid < nk) {
        int w = tid >> 6, rr = tid & 63;
        u64 kwv = sh.keep[w];
        if ((kwv >> rr) & 1ull) {
            int pos = __popcll(kwv & ((1ull << rr) - 1ull));
            for (int q = 0; q < w; ++q) pos += __popcll(sh.keep[q]);
            float* o = out + (((size_t)img * NUM_CLASSES + cl) * TOP_K + pos) * 5;
            o[0] = sh.score[tid];
            o[1] = sh.box[tid][0];
            o[2] = sh.box[tid][1];
            o[3] = sh.box[tid][2];
            o[4] = sh.box[tid][3];
        }
    }
}

extern "C" void kernel_launch(void* const* d_in, const int* in_sizes, int n_in,
                              void* d_out, int out_size, void* d_ws, size_t ws_size,
                              hipStream_t stream) {
    const float* loc   = (const float*)d_in[0];
    const float* conf  = (const float*)d_in[1];
    const float* prior = (const float*)d_in[2];
    float* out = (float*)d_out;

    hipMemsetAsync(d_out, 0, (size_t)out_size * sizeof(float), stream);

    // ws layout: [0, NTASK*4) counts | [65536, 65536 + NTASK*CAP*8) keys
    const size_t need = 65536 + (size_t)NTASK * CAP * 8;
    const int use_ws = (ws_size >= need) ? 1 : 0;   // constant per session -> deterministic

    u32* counts = (u32*)d_ws;
    u64* keys   = (u64*)((char*)d_ws + 65536);

    if (use_ws) {
        hipMemsetAsync(d_ws, 0, NTASK * sizeof(u32), stream);
        filter_kernel<<<FILTER_BLOCKS, 256, 0, stream>>>((const float4*)conf, counts, keys);
    }
    nms_kernel<<<NTASK, 256, 0, stream>>>(loc, conf, prior,
                                          use_ws ? counts : nullptr,
                                          use_ws ? keys : nullptr,
                                          out, use_ws);
}

// Round 9
// 120.375 us; speedup vs baseline: 1.7541x; 1.2397x over previous
//
#include <hip/hip_runtime.h>
#include <stdint.h>

#pragma clang fp contract(off)

#define NUM_CLASSES 81
#define TOP_K 200
#define BATCH 32
#define NUM_PRIORS 16384
#define CAP 512
#define CONF_T 0.01f
#define NMS_T 0.45f
#define PIVOT_S 0.97827148f
#define NTASK (BATCH * (NUM_CLASSES - 1))
#define QCAP 1536               // mean ~445 hits/block (256 rows), +50 sigma headroom
#define ROWS_PER_BLK 256
#define FILTER_BLOCKS 2048      // 64 chunks x 32 images
#define NB 1024                 // counting-sort buckets

typedef unsigned long long u64;
typedef unsigned int u32;

// Correctly-rounded f32 exp via f64 — verified bit-compatible R0-R8 (absmax 3e-8).
__device__ __forceinline__ float exp_ref(float x) {
#pragma clang fp contract(off)
    return (float)exp((double)x);
}

struct SharedBlk {
    u64 keys[CAP];                  // canonical keys: bits(score)<<32 | (u32)(~p)
    union {
        u64 sup[TOP_K][4];          // phase 4+: suppression bitmasks (6400 B)
        struct { u32 bcnt[NB]; u32 flag; } srt;  // phase 2: counting sort (4100 B)
    } a;
    union {
        struct { float box[TOP_K][5]; float score[TOP_K]; } bx;  // phase 3+ (4800 B)
        u64 keys2[CAP];             // phase 2: sorted output (4096 B)
    } b;
    u64 keep[4];
    u32 wsum[4];
    u32 acc;
    u32 ctr;
};

// Count elements with key > pivot (valid = score > CONF_T; invalid key == 0).
__device__ int count_pass(const float* cbase, u64 pivot, int tid, int lane, u32* s_acc) {
#pragma clang fp contract(off)
    __syncthreads();
    if (tid == 0) *s_acc = 0u;
    __syncthreads();
    u32 ph = (u32)(pivot >> 32), pl = (u32)pivot;
    u32 c = 0;
    for (int j = 0; j < 64; ++j) {
        int p = tid + (j << 8);
        float s = cbase[(size_t)p * NUM_CLASSES];
        bool valid = s > CONF_T;
        u32 bt = valid ? __float_as_uint(s) : 0u;
        u32 il = ~(u32)p;
        c += (valid && ((bt > ph) || ((bt == ph) && (il > pl)))) ? 1u : 0u;
    }
    for (int off = 32; off > 0; off >>= 1) c += __shfl_down(c, off, 64);
    if (lane == 0) atomicAdd(s_acc, c);
    __syncthreads();
    return (int)*s_acc;
}

// Count AND gather (capped at CAP) elements with key > pivot into s_keys.
__device__ int gather_pass(const float* cbase, u64 pivot, int tid, int lane,
                           u64* s_keys, u32* s_acc, u32* s_ctr) {
#pragma clang fp contract(off)
    __syncthreads();
    if (tid == 0) { *s_acc = 0u; *s_ctr = 0u; }
    for (int q = tid; q < CAP; q += 256) s_keys[q] = 0ull;
    __syncthreads();
    u32 ph = (u32)(pivot >> 32), pl = (u32)pivot;
    u32 cnt = 0;
    for (int j = 0; j < 64; ++j) {
        int p = tid + (j << 8);
        float s = cbase[(size_t)p * NUM_CLASSES];
        bool valid = s > CONF_T;
        u32 bt = valid ? __float_as_uint(s) : 0u;
        u32 il = ~(u32)p;
        bool pred = valid && ((bt > ph) || ((bt == ph) && (il > pl)));
        cnt += pred ? 1u : 0u;
        u64 mk = __ballot(pred);
        u32 off = 0;
        if (lane == 0 && mk) off = atomicAdd(s_ctr, (u32)__popcll(mk));
        off = __shfl(off, 0, 64);
        if (pred) {
            u32 pos = off + (u32)__popcll(mk & ((1ull << lane) - 1ull));
            if (pos < CAP) s_keys[pos] = ((u64)bt << 32) | il;
        }
    }
    for (int off2 = 32; off2 > 0; off2 >>= 1) cnt += __shfl_down(cnt, off2, 64);
    if (lane == 0) atomicAdd(s_acc, cnt);
    __syncthreads();
    return (int)*s_acc;
}

// Full bitonic sort of CAP u64 keys, descending (exact fallback path).
__device__ __forceinline__ void bitonic_desc(u64* k, int tid) {
    for (int k2 = 2; k2 <= CAP; k2 <<= 1) {
        for (int jj = k2 >> 1; jj > 0; jj >>= 1) {
            __syncthreads();
            for (int i = tid; i < CAP; i += 256) {
                int ixj = i ^ jj;
                if (ixj > i) {
                    u64 a = k[i], bb = k[ixj];
                    bool up = ((i & k2) == 0);
                    if (up ? (a < bb) : (a > bb)) { k[i] = bb; k[ixj] = a; }
                }
            }
        }
    }
    __syncthreads();
}

// ---- Kernel 1: coalesced filter (R8 structure — near stream floor).
__global__ __launch_bounds__(256) void filter_kernel(
    const float4* __restrict__ conf4,
    u32* __restrict__ counts, u64* __restrict__ keys)
{
#pragma clang fp contract(off)
    __shared__ u64 qkey[QCAP];
    __shared__ u32 tcnt[80];
    __shared__ u32 qn;

    const int tid = threadIdx.x;
    const int lane = tid & 63;
    const int bid = blockIdx.x;
    const int img = bid & 31;        // image pinned to one XCD (bid%8 fixed)
    const int chunk = bid >> 5;      // 64 chunks x 256 prior-rows
    const int row0 = img * NUM_PRIORS + chunk * ROWS_PER_BLK;
    const int base4 = row0 * NUM_CLASSES / 4;   // 256*81 = 20736 elems = 5184 float4

    if (tid == 0) qn = 0u;
    if (tid < 80) tcnt[tid] = 0u;
    __syncthreads();

    // 5184 float4 = 20*256 + 64
    #pragma unroll 4
    for (int it = 0; it < 21; ++it) {
        int le4 = tid + it * 256;
        if (it == 20 && tid >= 64) break;
        float4 v = conf4[base4 + le4];
        float vv[4] = {v.x, v.y, v.z, v.w};

        bool h0, h1, h2, h3;
        {
            u32 le0 = (u32)(le4 * 4);
            u32 r0 = le0 / NUM_CLASSES;            // magic-mul
            u32 c0 = le0 - r0 * NUM_CLASSES;
            h0 = (vv[0] > PIVOT_S) && (c0 != 0u);
            u32 c1 = c0 + 1u, c2 = c0 + 2u, c3 = c0 + 3u;
            h1 = (vv[1] > PIVOT_S) && (c1 != 81u);
            h2 = (vv[2] > PIVOT_S) && (c2 != 81u) && (c2 != 162u);
            h3 = (vv[3] > PIVOT_S) && (c3 != 81u) && (c3 != 162u);
        }
        u32 hc = (h0?1u:0u) + (h1?1u:0u) + (h2?1u:0u) + (h3?1u:0u);

        u64 b1 = __ballot(hc >= 1u);
        if (b1) {
            u64 b2 = __ballot(hc >= 2u);
            u64 b3 = __ballot(hc >= 3u);
            u64 b4 = __ballot(hc >= 4u);
            u32 tot = (u32)(__popcll(b1) + __popcll(b2) + __popcll(b3) + __popcll(b4));
            u32 base = 0;
            if (lane == 0) base = atomicAdd(&qn, tot);
            base = __shfl(base, 0, 64);
            if (hc) {
                u64 lt = (1ull << lane) - 1ull;
                u32 off = base + (u32)(__popcll(b1 & lt) + __popcll(b2 & lt)
                                     + __popcll(b3 & lt) + __popcll(b4 & lt));
                #pragma unroll
                for (int j = 0; j < 4; ++j) {
                    bool hj = (j == 0) ? h0 : (j == 1) ? h1 : (j == 2) ? h2 : h3;
                    if (hj) {
                        u32 le = (u32)(le4 * 4 + j);
                        u32 lrow = le / NUM_CLASSES;
                        u32 c = le - lrow * NUM_CLASSES;
                        u32 p = (u32)(chunk * ROWS_PER_BLK) + lrow;
                        u64 key = ((u64)__float_as_uint(vv[j]) << 32)
                                | ((u64)(16383u - p) << 7) | (u64)(c - 1u);
                        if (off < QCAP) qkey[off] = key;
                        ++off;
                    }
                }
            }
        }
    }
    __syncthreads();

    u32 qtotal = qn;
    u32 qvalid = qtotal < QCAP ? qtotal : QCAP;

    for (u32 q = tid; q < qvalid; q += 256)
        atomicAdd(&tcnt[(u32)(qkey[q] & 0x7Full)], 1u);
    __syncthreads();

    if (tid < 80) {
        u32 n = tcnt[tid];
        u32 base = 0;
        if (n) base = atomicAdd(&counts[img * 80 + tid], n);
        tcnt[tid] = base;
    }
    __syncthreads();

    for (u32 q = tid; q < qvalid; q += 256) {
        u64 k = qkey[q];
        u32 t = (u32)(k & 0x7Full);
        u32 slot = atomicAdd(&tcnt[t], 1u);
        if (slot < CAP) keys[(size_t)(img * 80 + t) * CAP + slot] = k;
    }
    if (qtotal > QCAP) {
        if (tid < 80) atomicAdd(&counts[img * 80 + tid], 0x01000000u);
    }
}

// ---- Kernel 2: per-(img,class) counting-sort + NMS.
__global__ __launch_bounds__(256) void nms_kernel(
    const float* __restrict__ loc_data,   // [B,P,4]
    const float* __restrict__ conf_data,  // [B*P,C]
    const float* __restrict__ prior_data, // [P,4]
    const u32* __restrict__ counts,       // [NTASK] (may be null)
    const u64* __restrict__ gkeys,        // [NTASK][CAP] (may be null)
    float* __restrict__ out,              // [B,C,K,5], pre-zeroed
    int use_ws)
{
#pragma clang fp contract(off)
    __shared__ SharedBlk sh;
    const int tid = threadIdx.x;
    const int lane = tid & 63;
    const int wv = tid >> 6;
    const int b = blockIdx.x;
    const int img = b / 80;
    const int r = b - img * 80;
    const int cl = r + 1;
    const int task = img * 80 + r;

    const float* cbase = conf_data + (size_t)img * NUM_PRIORS * NUM_CLASSES + cl;

    // ---- Phase 1: candidate set (ws fast path, else exact strided fallback)
    int m = -1;
    bool fast = false;
    if (use_ws) {
        u32 cnt = counts[task];
        if (cnt >= TOP_K && cnt <= CAP) {
            const u64* src = gkeys + (size_t)task * CAP;
            for (int q = tid; q < CAP; q += 256) {
                u64 k = 0ull;
                if (q < (int)cnt) {
                    u64 kw = src[q];
                    u32 p = 16383u - ((u32)(kw >> 7) & 0x3FFFu);
                    k = (kw & 0xFFFFFFFF00000000ull) | (u64)(u32)(~p);
                }
                sh.keys[q] = k;
            }
            m = (int)cnt;
            fast = true;
        }
    }
    if (m < 0) {
        u64 pivot = ((u64)__float_as_uint(PIVOT_S) << 32) | 0xFFFFFFFFull;
        m = gather_pass(cbase, pivot, tid, lane, sh.keys, &sh.acc, &sh.ctr);
        if (m < TOP_K || m > CAP) {
            const u32 B001 = __float_as_uint(CONF_T);
            int nvalid = count_pass(cbase, ((u64)B001 << 32) | 0xFFFFFFFFull, tid, lane, &sh.acc);
            if (nvalid <= CAP) {
                pivot = 0ull;  // gather all valid
            } else {
                u64 lo = ((u64)B001 << 32) | 0xFFFFFFFFull;
                u64 hi = ~0ull;
                for (int it = 0; it < 64; ++it) {
                    u64 mid = lo + ((hi - lo) >> 1);
                    int c = count_pass(cbase, mid, tid, lane, &sh.acc);
                    if (c >= TOP_K && c <= CAP) { pivot = mid; break; }
                    if (c > CAP) lo = mid; else hi = mid;
                }
            }
            m = gather_pass(cbase, pivot, tid, lane, sh.keys, &sh.acc, &sh.ctr);
        }
    }
    const int nk = m < TOP_K ? m : TOP_K;

    // ---- Phase 2: sort m keys descending.
    // Fast path: counting sort (scores all > PIVOT_S -> narrow bit range).
    // Fallback / pathological bucket: full bitonic (exact, rare).
    bool in_k2 = false;
    if (fast) {
        for (int i = tid; i < NB; i += 256) sh.a.srt.bcnt[i] = 0u;
        if (tid == 0) sh.a.srt.flag = 0u;
        __syncthreads();
        const u32 LOB = __float_as_uint(PIVOT_S);
        for (int q = tid; q < m; q += 256) {
            u32 sb = (u32)(sh.keys[q] >> 32);
            u32 bi = (sb - LOB - 1u) >> 9;
            if (bi > (u32)(NB - 1)) bi = (u32)(NB - 1);
            atomicAdd(&sh.a.srt.bcnt[(u32)(NB - 1) - bi], 1u);   // bucket asc = score desc
        }
        __syncthreads();
        // exclusive scan over NB bins (4 bins/thread, shfl wave-scan + cross-wave)
        u32 c0 = sh.a.srt.bcnt[tid * 4 + 0];
        u32 c1 = sh.a.srt.bcnt[tid * 4 + 1];
        u32 c2 = sh.a.srt.bcnt[tid * 4 + 2];
        u32 c3 = sh.a.srt.bcnt[tid * 4 + 3];
        u32 s = c0 + c1 + c2 + c3;
        u32 inc = s;
        #pragma unroll
        for (int o = 1; o < 64; o <<= 1) {
            u32 t = __shfl_up(inc, o, 64);
            if (lane >= o) inc += t;
        }
        if (lane == 63) sh.wsum[wv] = inc;
        __syncthreads();
        u32 wpre = 0;
        #pragma unroll
        for (int w = 0; w < 4; ++w) wpre += (w < wv) ? sh.wsum[w] : 0u;
        u32 ex = wpre + inc - s;
        sh.a.srt.bcnt[tid * 4 + 0] = ex;
        sh.a.srt.bcnt[tid * 4 + 1] = ex + c0;
        sh.a.srt.bcnt[tid * 4 + 2] = ex + c0 + c1;
        sh.a.srt.bcnt[tid * 4 + 3] = ex + c0 + c1 + c2;
        __syncthreads();
        // scatter (bins become end-cursors)
        for (int q = tid; q < m; q += 256) {
            u64 k = sh.keys[q];
            u32 sb = (u32)(k >> 32);
            u32 bi = (sb - LOB - 1u) >> 9;
            if (bi > (u32)(NB - 1)) bi = (u32)(NB - 1);
            u32 slot = atomicAdd(&sh.a.srt.bcnt[(u32)(NB - 1) - bi], 1u);
            sh.b.keys2[slot] = k;
        }
        __syncthreads();
        // per-bucket insertion sort desc (full 64-bit keys -> deterministic)
        for (int bb = tid; bb < NB; bb += 256) {
            u32 e = sh.a.srt.bcnt[bb];
            u32 st = bb ? sh.a.srt.bcnt[bb - 1] : 0u;
            if ((int)(e - st) > 32) { sh.a.srt.flag = 1u; continue; }
            for (u32 i = st + 1; i < e; ++i) {
                u64 x = sh.b.keys2[i];
                int j = (int)i - 1;
                while (j >= (int)st && sh.b.keys2[j] < x) {
                    sh.b.keys2[j + 1] = sh.b.keys2[j];
                    --j;
                }
                sh.b.keys2[j + 1] = x;
            }
        }
        __syncthreads();
        u32 fl = sh.a.srt.flag;
        if (!fl) in_k2 = true;
        else bitonic_desc(sh.keys, tid);    // ~impossible; exact fallback
    } else {
        bitonic_desc(sh.keys, tid);
    }

    // ---- Phase 3: decode candidate boxes (reference op order)
    {
        u64 key = 0ull;
        if (tid < nk) key = in_k2 ? sh.b.keys2[tid] : sh.keys[tid];
        float4 lc, pr;
        int p = 0;
        if (tid < nk) {
            p = (int)(~(u32)key);
            lc = *(const float4*)(loc_data + ((size_t)img * NUM_PRIORS + p) * 4);
            pr = *(const float4*)(prior_data + (size_t)p * 4);
        }
        __syncthreads();   // keys2 fully consumed before box overwrites it
        if (tid < nk) {
            float sc = __uint_as_float((u32)(key >> 32));
            float cx = pr.x + (lc.x * 0.1f) * pr.z;
            float cy = pr.y + (lc.y * 0.1f) * pr.w;
            float w  = pr.z * exp_ref(lc.z * 0.2f);
            float h  = pr.w * exp_ref(lc.w * 0.2f);
            float x1 = cx - 0.5f * w;
            float y1 = cy - 0.5f * h;
            float x2 = x1 + w;
            float y2 = y1 + h;
            sh.b.bx.box[tid][0] = x1; sh.b.bx.box[tid][1] = y1;
            sh.b.bx.box[tid][2] = x2; sh.b.bx.box[tid][3] = y2;
            sh.b.bx.box[tid][4] = fmaxf(x2 - x1, 0.0f) * fmaxf(y2 - y1, 0.0f);
            sh.b.bx.score[tid] = sc;
        }
    }
    __syncthreads();

    // ---- Phase 4: row-per-thread suppression masks (upper triangle, regs only).
    // Exact-div elimination: fl32(inter/denom) > 0.45f  <=>  inter > M45*denom,
    // M45 = (double)0.45f + 2^-26 (25-bit) x denom (24-bit) -> exact f64 product;
    // tie rounds to even mantissa (=0.45f) -> strict '>' . Bit-identical to ref.
    {
        const double M45 = (double)0.45f + 0x1p-26;
        u64 m0 = 0ull, m1 = 0ull, m2 = 0ull, m3 = 0ull;
        if (tid < nk) {
            const float bx0 = sh.b.bx.box[tid][0], by0 = sh.b.bx.box[tid][1];
            const float bx1 = sh.b.bx.box[tid][2], by1 = sh.b.bx.box[tid][3];
            const float aj  = sh.b.bx.box[tid][4];
            #pragma unroll
            for (int c = 0; c < 4; ++c) {
                u64 mm = 0ull;
                int klo = tid + 1 > (c << 6) ? tid + 1 : (c << 6);
                int khi = nk < ((c + 1) << 6) ? nk : ((c + 1) << 6);
                for (int k = klo; k < khi; ++k) {
                    float ltx = fmaxf(bx0, sh.b.bx.box[k][0]);
                    float lty = fmaxf(by0, sh.b.bx.box[k][1]);
                    float rbx = fminf(bx1, sh.b.bx.box[k][2]);
                    float rby = fminf(by1, sh.b.bx.box[k][3]);
                    float wx = fmaxf(rbx - ltx, 0.0f);
                    float wy = fmaxf(rby - lty, 0.0f);
                    float inter = wx * wy;
                    float uni = (aj + sh.b.bx.box[k][4]) - inter;
                    float denom = fmaxf(uni, 1e-12f);
                    if ((double)inter > M45 * (double)denom) mm |= 1ull << (k & 63);
                }
                if (c == 0) m0 = mm; else if (c == 1) m1 = mm;
                else if (c == 2) m2 = mm; else m3 = mm;
            }
        }
        if (tid < TOP_K) {
            sh.a.sup[tid][0] = m0; sh.a.sup[tid][1] = m1;
            sh.a.sup[tid][2] = m2; sh.a.sup[tid][3] = m3;
        }
    }
    __syncthreads();

    // ---- Phase 5: greedy resolve on wave 0 (64-bit chunks, shfl broadcast)
    if (wv == 0) {
        u64 kws[4];
        #pragma unroll
        for (int w = 0; w < 4; ++w) {
            int rem = nk - (w << 6);
            kws[w] = rem >= 64 ? ~0ull : (rem <= 0 ? 0ull : ((1ull << rem) - 1ull));
        }
        for (int c = 0; c < 4; ++c) {
            int row = (c << 6) + lane;
            u64 myrow = (row < TOP_K) ? sh.a.sup[row][c] : 0ull;
            u64 kw = kws[c];
            u64 nz = __ballot(myrow != 0ull);
            u64 t = kw & nz;
            while (t) {
                int j = __ffsll(t) - 1;
                u64 rj = __shfl(myrow, j, 64);
                kw &= ~rj;
                t &= ~(1ull << j);
                t &= kw;
            }
            kws[c] = kw;
            for (int w2 = c + 1; w2 < 4; ++w2) {
                u64 contrib = (row < TOP_K && ((kw >> lane) & 1ull)) ? sh.a.sup[row][w2] : 0ull;
                #pragma unroll
                for (int off = 32; off > 0; off >>= 1) contrib |= __shfl_xor(contrib, off, 64);
                kws[w2] &= ~contrib;
            }
        }
        if (lane == 0) {
            sh.keep[0] = kws[0]; sh.keep[1] = kws[1];
            sh.keep[2] = kws[2]; sh.keep[3] = kws[3];
        }
    }
    __syncthreads();

    // ---- Phase 6: stable compaction of kept rows
    if (tid < nk) {
        int w = tid >> 6, rr = tid & 63;
        u64 kwv = sh.keep[w];
        if ((kwv >> rr) & 1ull) {
            int pos = __popcll(kwv & ((1ull << rr) - 1ull));
            for (int q = 0; q < w; ++q) pos += __popcll(sh.keep[q]);
            float* o = out + (((size_t)img * NUM_CLASSES + cl) * TOP_K + pos) * 5;
            o[0] = sh.b.bx.score[tid];
            o[1] = sh.b.bx.box[tid][0];
            o[2] = sh.b.bx.box[tid][1];
            o[3] = sh.b.bx.box[tid][2];
            o[4] = sh.b.bx.box[tid][3];
        }
    }
}

extern "C" void kernel_launch(void* const* d_in, const int* in_sizes, int n_in,
                              void* d_out, int out_size, void* d_ws, size_t ws_size,
                              hipStream_t stream) {
    const float* loc   = (const float*)d_in[0];
    const float* conf  = (const float*)d_in[1];
    const float* prior = (const float*)d_in[2];
    float* out = (float*)d_out;

    hipMemsetAsync(d_out, 0, (size_t)out_size * sizeof(float), stream);

    // ws layout: [0, NTASK*4) counts | [65536, 65536 + NTASK*CAP*8) keys
    const size_t need = 65536 + (size_t)NTASK * CAP * 8;
    const int use_ws = (ws_size >= need) ? 1 : 0;   // constant per session -> deterministic

    u32* counts = (u32*)d_ws;
    u64* keys   = (u64*)((char*)d_ws + 65536);

    if (use_ws) {
        hipMemsetAsync(d_ws, 0, NTASK * sizeof(u32), stream);
        filter_kernel<<<FILTER_BLOCKS, 256, 0, stream>>>((const float4*)conf, counts, keys);
    }
    nms_kernel<<<NTASK, 256, 0, stream>>>(loc, conf, prior,
                                          use_ws ? counts : nullptr,
                                          use_ws ? keys : nullptr,
                                          out, use_ws);
}